// Round 7
// baseline (211.243 us; speedup 1.0000x reference)
//
#include <hip/hip_runtime.h>
#include <utility>

#define BB 16
#define TT 2048
#define DD 768
#define HH 96

typedef __attribute__((ext_vector_type(8))) short bf16x8;
typedef __attribute__((ext_vector_type(4))) short bf16x4;
typedef __attribute__((ext_vector_type(4))) float f32x4;

static __device__ __forceinline__ unsigned short f2bf(float f) {
  unsigned u = __builtin_bit_cast(unsigned, f);
  u = (u + 0x7fffu + ((u >> 16) & 1u)) >> 16;   // round-to-nearest-even
  return (unsigned short)u;
}

// ---------------- W convert: Wt[w][n][k] bf16, w order = {q,k,v} ----------------
__global__ void wconv(const float* __restrict__ Wk, const float* __restrict__ Wq,
                      const float* __restrict__ Wv, unsigned short* __restrict__ Wt) {
  int idx = blockIdx.x * 256 + threadIdx.x;
  if (idx >= 3 * HH * DD) return;
  int w = idx / (HH * DD);
  int rem = idx - w * (HH * DD);
  int n = rem / DD;
  int k = rem - n * DD;
  const float* W = (w == 0) ? Wq : (w == 1) ? Wk : Wv;
  Wt[idx] = f2bf(W[k * HH + n]);
}

// ---------------- QKV projection: independent-wave streaming GEMM ----------------
// block = 4 waves x 16 rows, one of {Q,K,V} per block (outsel = blk%3). Grid 1536
// -> 6 blocks/CU; launch_bounds(256,4) -> 16 independent waves/CU. No barriers,
// no LDS in the main loop. x prefetched 3 K-steps deep (HBM window), W-third
// prefetched 2 deep (L2 window). acc[6]=24 VGPR; total ~115 -> no spill at 128.
__global__ __launch_bounds__(256, 4) void qkv_proj(
    const float* __restrict__ x, const unsigned short* __restrict__ Wt,
    unsigned short* __restrict__ Qb, unsigned short* __restrict__ Kb,
    unsigned short* __restrict__ Vt) {
  __shared__ unsigned short vst[HH][72];   // V transpose staging (epilogue only)
  const int tid = threadIdx.x;
  const int lane = tid & 63;
  const int w = tid >> 6;
  const int g = lane >> 4;
  const int m = lane & 15;
  const int blk = (int)blockIdx.x;
  const int tile = blk / 3;
  const int outsel = blk - tile * 3;       // 0=Q 1=K 2=V
  const long r0 = (long)tile * 64;
  const long rw = r0 + w * 16;

  f32x4 acc[6];
#pragma unroll
  for (int nf = 0; nf < 6; ++nf) { acc[nf][0] = 0.f; acc[nf][1] = 0.f; acc[nf][2] = 0.f; acc[nf][3] = 0.f; }

  const float* xrow = x + (rw + m) * DD + g * 8;
  const unsigned short* wrow = Wt + ((long)outsel * HH + m) * DD + g * 8;

  f32x4 xa[3][2];                          // x triple-buffer: 3 K-steps in flight
  bf16x8 wf[2][6];                         // W double-buffer: 2 K-steps in flight

  // prologue
#pragma unroll
  for (int t = 0; t < 3; ++t) {
    xa[t][0] = *(const f32x4*)(xrow + t * 32);
    xa[t][1] = *(const f32x4*)(xrow + t * 32 + 4);
  }
#pragma unroll
  for (int t = 0; t < 2; ++t)
#pragma unroll
    for (int nf = 0; nf < 6; ++nf)
      wf[t][nf] = *(const bf16x8*)(wrow + (nf * 16) * DD + t * 32);

#pragma unroll
  for (int t = 0; t < 24; ++t) {
    const int PX = t % 3;
    const int PW = t & 1;
    // pack A-frag (waits only on x(t), issued 3 phases ago)
    bf16x8 a;
    {
      f32x4 lo = xa[PX][0], hi = xa[PX][1];
#pragma unroll
      for (int jj = 0; jj < 4; ++jj) { a[jj] = (short)f2bf(lo[jj]); a[4 + jj] = (short)f2bf(hi[jj]); }
    }
    // refill x buffer for t+3
    if (t + 3 < 24) {
      xa[PX][0] = *(const f32x4*)(xrow + (t + 3) * 32);
      xa[PX][1] = *(const f32x4*)(xrow + (t + 3) * 32 + 4);
    }
    // MFMAs (waits only on W(t), issued 2 phases ago)
#pragma unroll
    for (int nf = 0; nf < 6; ++nf)
      acc[nf] = __builtin_amdgcn_mfma_f32_16x16x32_bf16(a, wf[PW][nf], acc[nf], 0, 0, 0);
    // refill W buffer for t+2
    if (t + 2 < 24) {
#pragma unroll
      for (int nf = 0; nf < 6; ++nf)
        wf[PW][nf] = *(const bf16x8*)(wrow + (nf * 16) * DD + (t + 2) * 32);
    }
  }

  // ---------------- epilogue ----------------
  if (outsel == 0) {
#pragma unroll
    for (int nf = 0; nf < 6; ++nf)
#pragma unroll
      for (int r = 0; r < 4; ++r)
        Qb[(rw + 4 * g + r) * HH + nf * 16 + m] = f2bf(acc[nf][r]);
  } else if (outsel == 1) {
#pragma unroll
    for (int nf = 0; nf < 6; ++nf)
#pragma unroll
      for (int r = 0; r < 4; ++r)
        Kb[(rw + 4 * g + r) * HH + nf * 16 + m] = f2bf(acc[nf][r]);
  } else {
#pragma unroll
    for (int nf = 0; nf < 6; ++nf)
#pragma unroll
      for (int r = 0; r < 4; ++r)
        vst[nf * 16 + m][w * 16 + 4 * g + r] = f2bf(acc[nf][r]);
    __syncthreads();
    // Vt[b][h][t]: 96*64/8 = 768 chunks, 3 per thread, coalesced along t
    const int bidx = (int)(r0 >> 11);
    const int t0 = (int)(r0 & 2047);
#pragma unroll
    for (int jj = 0; jj < 3; ++jj) {
      int flat = tid + jj * 256;
      int h = flat >> 3;
      int t8 = (flat & 7) * 8;
      bf16x8 v = *(const bf16x8*)(&vst[h][t8]);
      *(bf16x8*)(Vt + ((long)(bidx * HH + h) * TT + t0 + t8)) = v;
    }
  }
}

// ---------------- flash attention, async 2-phase pipeline (unchanged) ----------------
__global__ __launch_bounds__(256, 2) void attn(
    const unsigned short* __restrict__ Qb, const unsigned short* __restrict__ Kb,
    const unsigned short* __restrict__ Vt, float* __restrict__ out) {
  __shared__ unsigned short Klds[2][64 * 104];   // 64 rows x (96 data + 8 pad)
  __shared__ unsigned short Vlds[2][96 * 72];    // 96 rows x (64 data + 8 pad)
  const int tid = threadIdx.x;
  const int lane = tid & 63;
  const int w = tid >> 6;
  const int g = lane >> 4;
  const int c = lane & 15;

  const int blk = (int)blockIdx.x;
  const int b = ((blk & 7) << 1) + ((blk >> 3) & 1);
  const int qt = 31 - (blk >> 4);
  const int q0 = qt * 64;
  const int lastkt = qt;

  bf16x8 qf[3];
  {
    const unsigned short* qrow = Qb + ((long)b * TT + q0 + 4 * c + w) * HH;
#pragma unroll
    for (int ks = 0; ks < 3; ++ks) qf[ks] = *(const bf16x8*)(qrow + ks * 32 + g * 8);
  }

  const unsigned short* Kbase = Kb + (long)b * TT * HH;
  const unsigned short* Vbase = Vt + (long)b * HH * TT;

  f32x4 o[6];
#pragma unroll
  for (int nf = 0; nf < 6; ++nf) { o[nf][0] = 0.f; o[nf][1] = 0.f; o[nf][2] = 0.f; o[nf][3] = 0.f; }
  float m_run = -1e30f, l_run = 0.f;
  const float SCL = 0.10206207261596577f * 1.44269504088896f;  // HS^-0.5 * log2(e)

  bf16x8 kreg[2][3], vreg[2][3];

  auto issue = [&](auto PC, int t) {
    constexpr int P = decltype(PC)::value;
    if (t <= lastkt) {
      const unsigned short* ksrc = Kbase + (long)t * 64 * HH;
#pragma unroll
      for (int i = 0; i < 3; ++i) kreg[P][i] = *(const bf16x8*)(ksrc + (tid + i * 256) * 8);
#pragma unroll
      for (int i = 0; i < 3; ++i) {
        int j = tid + i * 256;
        vreg[P][i] = *(const bf16x8*)(Vbase + (long)(j >> 3) * TT + t * 64 + (j & 7) * 8);
      }
    }
  };
  auto lwrite = [&](auto PC, int t) {
    constexpr int P = decltype(PC)::value;
    if (t <= lastkt) {
#pragma unroll
      for (int i = 0; i < 3; ++i) {
        int j = tid + i * 256;
        int row = j / 12, gs = j - row * 12;
        *(bf16x8*)(&Klds[P][row * 104 + gs * 8]) = kreg[P][i];
      }
#pragma unroll
      for (int i = 0; i < 3; ++i) {
        int j = tid + i * 256;
        *(bf16x8*)(&Vlds[P][(j >> 3) * 72 + (j & 7) * 8]) = vreg[P][i];
      }
    }
  };
  auto bar = [&]() {
    asm volatile("s_waitcnt lgkmcnt(0)" ::: "memory");
    __builtin_amdgcn_s_barrier();
    __builtin_amdgcn_sched_barrier(0);
  };
  auto compute = [&](auto PC, int t) {
    constexpr int P = decltype(PC)::value;
    const int kv0 = t * 64;
    f32x4 s[4];
#pragma unroll
    for (int mf = 0; mf < 4; ++mf) { s[mf][0] = 0.f; s[mf][1] = 0.f; s[mf][2] = 0.f; s[mf][3] = 0.f; }
#pragma unroll
    for (int ks = 0; ks < 3; ++ks) {
      bf16x8 kb_[4];
#pragma unroll
      for (int mf = 0; mf < 4; ++mf)
        kb_[mf] = *(const bf16x8*)(&Klds[P][(mf * 16 + c) * 104 + ks * 32 + g * 8]);
#pragma unroll
      for (int mf = 0; mf < 4; ++mf)
        s[mf] = __builtin_amdgcn_mfma_f32_16x16x32_bf16(kb_[mf], qf[ks], s[mf], 0, 0, 0);
    }
    const int qcol = q0 + 4 * c + w;
    const bool diag = (t == lastkt);
    float smax = -1e30f;
#pragma unroll
    for (int mf = 0; mf < 4; ++mf)
#pragma unroll
      for (int r = 0; r < 4; ++r) {
        float v = s[mf][r] * SCL;
        if (diag && (kv0 + mf * 16 + 4 * g + r) > qcol) v = -1e30f;
        s[mf][r] = v;
        smax = fmaxf(smax, v);
      }
    smax = fmaxf(smax, __shfl_xor(smax, 16));
    smax = fmaxf(smax, __shfl_xor(smax, 32));
    const float m_new = fmaxf(m_run, smax);
    const float corr = __builtin_amdgcn_exp2f(m_run - m_new);
    float rsum = 0.f;
    unsigned short pb[4][4];
#pragma unroll
    for (int mf = 0; mf < 4; ++mf)
#pragma unroll
      for (int r = 0; r < 4; ++r) {
        float p = __builtin_amdgcn_exp2f(s[mf][r] - m_new);
        rsum += p;
        pb[mf][r] = f2bf(p);
      }
    rsum += __shfl_xor(rsum, 16);
    rsum += __shfl_xor(rsum, 32);
    l_run = l_run * corr + rsum;
    m_run = m_new;
#pragma unroll
    for (int r = 0; r < 4; ++r) {
      float cr = __shfl(corr, 4 * g + r);
#pragma unroll
      for (int nf = 0; nf < 6; ++nf) o[nf][r] *= cr;
    }
#pragma unroll
    for (int kf = 0; kf < 2; ++kf) {
      bf16x8 a;
#pragma unroll
      for (int i = 0; i < 8; ++i) a[i] = (short)pb[2 * kf + (i >> 2)][i & 3];
#pragma unroll
      for (int nf = 0; nf < 6; ++nf) {
        const unsigned short* vr = &Vlds[P][(nf * 16 + c) * 72 + kf * 32 + 4 * g];
        bf16x4 lo = *(const bf16x4*)(vr);
        bf16x4 hi = *(const bf16x4*)(vr + 16);
        bf16x8 vf = __builtin_shufflevector(lo, hi, 0, 1, 2, 3, 4, 5, 6, 7);
        o[nf] = __builtin_amdgcn_mfma_f32_16x16x32_bf16(a, vf, o[nf], 0, 0, 0);
      }
    }
  };

  std::integral_constant<int, 0> P0;
  std::integral_constant<int, 1> P1;

  issue(P0, 0);
  issue(P1, 1);
  lwrite(P0, 0);
  bar();

  for (int t = 0; t <= lastkt; t += 2) {
    issue(P0, t + 2);
    compute(P0, t);
    lwrite(P1, t + 1);
    bar();
    if (t + 1 <= lastkt) {
      issue(P1, t + 3);
      compute(P1, t + 1);
      lwrite(P0, t + 2);
      bar();
    }
  }

  const float inv = 1.0f / l_run;
#pragma unroll
  for (int r = 0; r < 4; ++r) {
    float ivr = __shfl(inv, 4 * g + r);
    long orow = ((long)b * TT + q0 + 16 * g + 4 * r + w) * HH;
#pragma unroll
    for (int nf = 0; nf < 6; ++nf) out[orow + nf * 16 + c] = o[nf][r] * ivr;
  }
}

extern "C" void kernel_launch(void* const* d_in, const int* in_sizes, int n_in,
                              void* d_out, int out_size, void* d_ws, size_t ws_size,
                              hipStream_t stream) {
  const float* x  = (const float*)d_in[0];
  const float* Wk = (const float*)d_in[1];
  const float* Wq = (const float*)d_in[2];
  const float* Wv = (const float*)d_in[3];
  float* out = (float*)d_out;

  unsigned short* Wt = (unsigned short*)d_ws;        // 3*96*768 bf16 = 442 KB
  unsigned short* Qb = Wt + 3 * HH * DD;             // [B*T][96] bf16
  unsigned short* Kb = Qb + (long)BB * TT * HH;      // [B*T][96] bf16
  unsigned short* Vt = Kb + (long)BB * TT * HH;      // [B][96][T] bf16 (transposed)

  wconv<<<dim3((3 * HH * DD + 255) / 256), dim3(256), 0, stream>>>(Wk, Wq, Wv, Wt);
  qkv_proj<<<dim3(3 * BB * TT / 64), dim3(256), 0, stream>>>(x, Wt, Qb, Kb, Vt);
  attn<<<dim3(512), dim3(256), 0, stream>>>(Qb, Kb, Vt, out);
}

// Round 8
// 93.187 us; speedup vs baseline: 2.2669x; 2.2669x over previous
//
#include <hip/hip_runtime.h>
#include <utility>

#define BB 16
#define TT 2048
#define DD 768
#define HH 96

typedef __attribute__((ext_vector_type(8))) short bf16x8;
typedef __attribute__((ext_vector_type(4))) short bf16x4;
typedef __attribute__((ext_vector_type(4))) float f32x4;

static __device__ __forceinline__ unsigned short f2bf(float f) {
  unsigned u = __builtin_bit_cast(unsigned, f);
  u = (u + 0x7fffu + ((u >> 16) & 1u)) >> 16;   // round-to-nearest-even
  return (unsigned short)u;
}

// ---------------- W convert: Wt[w][n][k] bf16, w order = {q,k,v} ----------------
__global__ void wconv(const float* __restrict__ Wk, const float* __restrict__ Wq,
                      const float* __restrict__ Wv, unsigned short* __restrict__ Wt) {
  int idx = blockIdx.x * 256 + threadIdx.x;
  if (idx >= 3 * HH * DD) return;
  int w = idx / (HH * DD);
  int rem = idx - w * (HH * DD);
  int n = rem / DD;
  int k = rem - n * DD;
  const float* W = (w == 0) ? Wq : (w == 1) ? Wk : Wv;
  Wt[idx] = f2bf(W[k * HH + n]);
}

// ---------------- QKV projection: coalesced glds pipeline, counted vmcnt ----------------
// grid 512 (64 rows), block 384 = 6 waves ({Q,K,V} x 2 row-groups of 32).
// BK=32, 24 phases. BOTH operands staged via global_load_lds with contiguous
// multi-row granules (x: 8 rows x 128B/instr; W: 16 rows x 64B/instr) -> ~8
// segments per instruction instead of 64 (the r4-r7 scatter bug). Per-wave
// 4-5 glds per phase; counted vmcnt, loads issued 2 phases before use. No
// VGPR loads in the main loop.
__global__ __launch_bounds__(384, 3) void qkv_proj(
    const float* __restrict__ x, const unsigned short* __restrict__ Wt,
    unsigned short* __restrict__ Qb, unsigned short* __restrict__ Kb,
    unsigned short* __restrict__ Vt) {
  __shared__ float Xlds[2][64 * 32];             // 2 x 8 KB
  __shared__ unsigned short Wlds[2][288 * 32];   // 2 x 18 KB
  const int tid = threadIdx.x;
  const int lane = tid & 63;
  const int w = tid >> 6;
  const int g = lane >> 4;
  const int m = lane & 15;
  const int outsel = w % 3;                // 0=Q 1=K 2=V
  const int rg = w / 3;                    // row-group (32 rows)
  const long r0 = (long)blockIdx.x * 64;
  const long rw = r0 + rg * 32;

  f32x4 acc[2][6];
#pragma unroll
  for (int u = 0; u < 2; ++u)
#pragma unroll
    for (int nf = 0; nf < 6; ++nf) { acc[u][nf][0] = 0.f; acc[u][nf][1] = 0.f; acc[u][nf][2] = 0.f; acc[u][nf][3] = 0.f; }

  // stage K-step t into buffer P. W: 18 granules (16 rows x 64B, lane=(row&15)*4+(col16)),
  // x: 8 granules (8 rows x 128B). Wave w takes granules i = w, w+6, ... ->
  // per-wave glds count: waves 0,1 -> 5; waves 2..5 -> 4.
  auto stage = [&](int P, int t) {
#pragma unroll
    for (int i = w; i < 18; i += 6) {
      const unsigned short* src = Wt + (long)(i * 16 + (lane >> 2)) * DD + t * 32 + (lane & 3) * 8;
      __builtin_amdgcn_global_load_lds(
          (const __attribute__((address_space(1))) void*)src,
          (__attribute__((address_space(3))) void*)(&Wlds[P][i * 512]), 16, 0, 0);
    }
#pragma unroll
    for (int i = w; i < 8; i += 6) {
      const float* src = x + (r0 + i * 8 + (lane >> 3)) * DD + t * 32 + (lane & 7) * 4;
      __builtin_amdgcn_global_load_lds(
          (const __attribute__((address_space(1))) void*)src,
          (__attribute__((address_space(3))) void*)(&Xlds[P][i * 256]), 16, 0, 0);
    }
  };

  auto compute = [&](int P) {
    bf16x8 a[2];
#pragma unroll
    for (int u = 0; u < 2; ++u) {
      const int row = rg * 32 + u * 16 + m;
      f32x4 lo = *(const f32x4*)(&Xlds[P][row * 32 + g * 8]);
      f32x4 hi = *(const f32x4*)(&Xlds[P][row * 32 + g * 8 + 4]);
#pragma unroll
      for (int jj = 0; jj < 4; ++jj) { a[u][jj] = (short)f2bf(lo[jj]); a[u][4 + jj] = (short)f2bf(hi[jj]); }
    }
#pragma unroll
    for (int nf = 0; nf < 6; ++nf) {
      bf16x8 wf = *(const bf16x8*)(&Wlds[P][(outsel * 96 + nf * 16 + m) * 32 + g * 8]);
      acc[0][nf] = __builtin_amdgcn_mfma_f32_16x16x32_bf16(a[0], wf, acc[0][nf], 0, 0, 0);
      acc[1][nf] = __builtin_amdgcn_mfma_f32_16x16x32_bf16(a[1], wf, acc[1][nf], 0, 0, 0);
    }
  };

  auto phase = [&](int t, int drain) {
    if (drain) { asm volatile("s_waitcnt vmcnt(0)" ::: "memory"); }
    else if (w < 2) { asm volatile("s_waitcnt vmcnt(5)" ::: "memory"); }
    else { asm volatile("s_waitcnt vmcnt(4)" ::: "memory"); }
    __builtin_amdgcn_sched_barrier(0);
    __builtin_amdgcn_s_barrier();
    __builtin_amdgcn_sched_barrier(0);
    compute(t & 1);
    asm volatile("s_waitcnt lgkmcnt(0)" ::: "memory");
    __builtin_amdgcn_sched_barrier(0);
    __builtin_amdgcn_s_barrier();
    __builtin_amdgcn_sched_barrier(0);
  };

  stage(0, 0);
  stage(1, 1);
  __builtin_amdgcn_sched_barrier(0);
  for (int t = 0; t < 22; ++t) {           // steady phases: stage t+2 after compute t
    phase(t, 0);
    stage(t & 1, t + 2);
    __builtin_amdgcn_sched_barrier(0);
  }
  phase(22, 0);
  phase(23, 1);

  // ---------------- epilogue ----------------
  unsigned short (*vst)[72] = (unsigned short (*)[72])(&Xlds[0][0]);  // 13.8 KB alias
  if (outsel == 0) {
#pragma unroll
    for (int u = 0; u < 2; ++u)
#pragma unroll
      for (int nf = 0; nf < 6; ++nf)
#pragma unroll
        for (int r = 0; r < 4; ++r)
          Qb[(rw + u * 16 + 4 * g + r) * HH + nf * 16 + m] = f2bf(acc[u][nf][r]);
  } else if (outsel == 1) {
#pragma unroll
    for (int u = 0; u < 2; ++u)
#pragma unroll
      for (int nf = 0; nf < 6; ++nf)
#pragma unroll
        for (int r = 0; r < 4; ++r)
          Kb[(rw + u * 16 + 4 * g + r) * HH + nf * 16 + m] = f2bf(acc[u][nf][r]);
  } else {
#pragma unroll
    for (int u = 0; u < 2; ++u)
#pragma unroll
      for (int nf = 0; nf < 6; ++nf)
#pragma unroll
        for (int r = 0; r < 4; ++r)
          vst[nf * 16 + m][rg * 32 + u * 16 + 4 * g + r] = f2bf(acc[u][nf][r]);
  }
  __syncthreads();
  // Vt[b][h][t]: 96*64/8 = 768 chunks, 2 per thread, coalesced along t
  const int bidx = (int)(r0 >> 11);
  const int t0 = (int)(r0 & 2047);
#pragma unroll
  for (int jj = 0; jj < 2; ++jj) {
    int flat = tid + jj * 384;
    int h = flat >> 3;
    int t8 = (flat & 7) * 8;
    bf16x8 v = *(const bf16x8*)(&vst[h][t8]);
    *(bf16x8*)(Vt + ((long)(bidx * HH + h) * TT + t0 + t8)) = v;
  }
}

// ---------------- flash attention, async 2-phase pipeline (unchanged) ----------------
__global__ __launch_bounds__(256, 2) void attn(
    const unsigned short* __restrict__ Qb, const unsigned short* __restrict__ Kb,
    const unsigned short* __restrict__ Vt, float* __restrict__ out) {
  __shared__ unsigned short Klds[2][64 * 104];   // 64 rows x (96 data + 8 pad)
  __shared__ unsigned short Vlds[2][96 * 72];    // 96 rows x (64 data + 8 pad)
  const int tid = threadIdx.x;
  const int lane = tid & 63;
  const int w = tid >> 6;
  const int g = lane >> 4;
  const int c = lane & 15;

  const int blk = (int)blockIdx.x;
  const int b = ((blk & 7) << 1) + ((blk >> 3) & 1);
  const int qt = 31 - (blk >> 4);
  const int q0 = qt * 64;
  const int lastkt = qt;

  bf16x8 qf[3];
  {
    const unsigned short* qrow = Qb + ((long)b * TT + q0 + 4 * c + w) * HH;
#pragma unroll
    for (int ks = 0; ks < 3; ++ks) qf[ks] = *(const bf16x8*)(qrow + ks * 32 + g * 8);
  }

  const unsigned short* Kbase = Kb + (long)b * TT * HH;
  const unsigned short* Vbase = Vt + (long)b * HH * TT;

  f32x4 o[6];
#pragma unroll
  for (int nf = 0; nf < 6; ++nf) { o[nf][0] = 0.f; o[nf][1] = 0.f; o[nf][2] = 0.f; o[nf][3] = 0.f; }
  float m_run = -1e30f, l_run = 0.f;
  const float SCL = 0.10206207261596577f * 1.44269504088896f;  // HS^-0.5 * log2(e)

  bf16x8 kreg[2][3], vreg[2][3];

  auto issue = [&](auto PC, int t) {
    constexpr int P = decltype(PC)::value;
    if (t <= lastkt) {
      const unsigned short* ksrc = Kbase + (long)t * 64 * HH;
#pragma unroll
      for (int i = 0; i < 3; ++i) kreg[P][i] = *(const bf16x8*)(ksrc + (tid + i * 256) * 8);
#pragma unroll
      for (int i = 0; i < 3; ++i) {
        int j = tid + i * 256;
        vreg[P][i] = *(const bf16x8*)(Vbase + (long)(j >> 3) * TT + t * 64 + (j & 7) * 8);
      }
    }
  };
  auto lwrite = [&](auto PC, int t) {
    constexpr int P = decltype(PC)::value;
    if (t <= lastkt) {
#pragma unroll
      for (int i = 0; i < 3; ++i) {
        int j = tid + i * 256;
        int row = j / 12, gs = j - row * 12;
        *(bf16x8*)(&Klds[P][row * 104 + gs * 8]) = kreg[P][i];
      }
#pragma unroll
      for (int i = 0; i < 3; ++i) {
        int j = tid + i * 256;
        *(bf16x8*)(&Vlds[P][(j >> 3) * 72 + (j & 7) * 8]) = vreg[P][i];
      }
    }
  };
  auto bar = [&]() {
    asm volatile("s_waitcnt lgkmcnt(0)" ::: "memory");
    __builtin_amdgcn_s_barrier();
    __builtin_amdgcn_sched_barrier(0);
  };
  auto compute = [&](auto PC, int t) {
    constexpr int P = decltype(PC)::value;
    const int kv0 = t * 64;
    f32x4 s[4];
#pragma unroll
    for (int mf = 0; mf < 4; ++mf) { s[mf][0] = 0.f; s[mf][1] = 0.f; s[mf][2] = 0.f; s[mf][3] = 0.f; }
#pragma unroll
    for (int ks = 0; ks < 3; ++ks) {
      bf16x8 kb_[4];
#pragma unroll
      for (int mf = 0; mf < 4; ++mf)
        kb_[mf] = *(const bf16x8*)(&Klds[P][(mf * 16 + c) * 104 + ks * 32 + g * 8]);
#pragma unroll
      for (int mf = 0; mf < 4; ++mf)
        s[mf] = __builtin_amdgcn_mfma_f32_16x16x32_bf16(kb_[mf], qf[ks], s[mf], 0, 0, 0);
    }
    const int qcol = q0 + 4 * c + w;
    const bool diag = (t == lastkt);
    float smax = -1e30f;
#pragma unroll
    for (int mf = 0; mf < 4; ++mf)
#pragma unroll
      for (int r = 0; r < 4; ++r) {
        float v = s[mf][r] * SCL;
        if (diag && (kv0 + mf * 16 + 4 * g + r) > qcol) v = -1e30f;
        s[mf][r] = v;
        smax = fmaxf(smax, v);
      }
    smax = fmaxf(smax, __shfl_xor(smax, 16));
    smax = fmaxf(smax, __shfl_xor(smax, 32));
    const float m_new = fmaxf(m_run, smax);
    const float corr = __builtin_amdgcn_exp2f(m_run - m_new);
    float rsum = 0.f;
    unsigned short pb[4][4];
#pragma unroll
    for (int mf = 0; mf < 4; ++mf)
#pragma unroll
      for (int r = 0; r < 4; ++r) {
        float p = __builtin_amdgcn_exp2f(s[mf][r] - m_new);
        rsum += p;
        pb[mf][r] = f2bf(p);
      }
    rsum += __shfl_xor(rsum, 16);
    rsum += __shfl_xor(rsum, 32);
    l_run = l_run * corr + rsum;
    m_run = m_new;
#pragma unroll
    for (int r = 0; r < 4; ++r) {
      float cr = __shfl(corr, 4 * g + r);
#pragma unroll
      for (int nf = 0; nf < 6; ++nf) o[nf][r] *= cr;
    }
#pragma unroll
    for (int kf = 0; kf < 2; ++kf) {
      bf16x8 a;
#pragma unroll
      for (int i = 0; i < 8; ++i) a[i] = (short)pb[2 * kf + (i >> 2)][i & 3];
#pragma unroll
      for (int nf = 0; nf < 6; ++nf) {
        const unsigned short* vr = &Vlds[P][(nf * 16 + c) * 72 + kf * 32 + 4 * g];
        bf16x4 lo = *(const bf16x4*)(vr);
        bf16x4 hi = *(const bf16x4*)(vr + 16);
        bf16x8 vf = __builtin_shufflevector(lo, hi, 0, 1, 2, 3, 4, 5, 6, 7);
        o[nf] = __builtin_amdgcn_mfma_f32_16x16x32_bf16(a, vf, o[nf], 0, 0, 0);
      }
    }
  };

  std::integral_constant<int, 0> P0;
  std::integral_constant<int, 1> P1;

  issue(P0, 0);
  issue(P1, 1);
  lwrite(P0, 0);
  bar();

  for (int t = 0; t <= lastkt; t += 2) {
    issue(P0, t + 2);
    compute(P0, t);
    lwrite(P1, t + 1);
    bar();
    if (t + 1 <= lastkt) {
      issue(P1, t + 3);
      compute(P1, t + 1);
      lwrite(P0, t + 2);
      bar();
    }
  }

  const float inv = 1.0f / l_run;
#pragma unroll
  for (int r = 0; r < 4; ++r) {
    float ivr = __shfl(inv, 4 * g + r);
    long orow = ((long)b * TT + q0 + 16 * g + 4 * r + w) * HH;
#pragma unroll
    for (int nf = 0; nf < 6; ++nf) out[orow + nf * 16 + c] = o[nf][r] * ivr;
  }
}

extern "C" void kernel_launch(void* const* d_in, const int* in_sizes, int n_in,
                              void* d_out, int out_size, void* d_ws, size_t ws_size,
                              hipStream_t stream) {
  const float* x  = (const float*)d_in[0];
  const float* Wk = (const float*)d_in[1];
  const float* Wq = (const float*)d_in[2];
  const float* Wv = (const float*)d_in[3];
  float* out = (float*)d_out;

  unsigned short* Wt = (unsigned short*)d_ws;        // 3*96*768 bf16 = 442 KB
  unsigned short* Qb = Wt + 3 * HH * DD;             // [B*T][96] bf16
  unsigned short* Kb = Qb + (long)BB * TT * HH;      // [B*T][96] bf16
  unsigned short* Vt = Kb + (long)BB * TT * HH;      // [B][96][T] bf16 (transposed)

  wconv<<<dim3((3 * HH * DD + 255) / 256), dim3(256), 0, stream>>>(Wk, Wq, Wv, Wt);
  qkv_proj<<<dim3(BB * TT / 64), dim3(384), 0, stream>>>(x, Wt, Qb, Kb, Vt);
  attn<<<dim3(512), dim3(256), 0, stream>>>(Qb, Kb, Vt, out);
}